// Round 4
// baseline (697.753 us; speedup 1.0000x reference)
//
#include <hip/hip_runtime.h>
#include <hip/hip_bf16.h>

// ---------- types / helpers ----------
typedef __bf16 bf16x8 __attribute__((ext_vector_type(8)));
typedef float  f32x4  __attribute__((ext_vector_type(4)));
typedef unsigned int u32;
typedef u32 u32x4 __attribute__((ext_vector_type(4)));
typedef unsigned short ushort_t;

__device__ inline float bf2f(ushort_t h) {
    union { u32 u; float f; } v; v.u = ((u32)h) << 16; return v.f;
}
__device__ inline ushort_t f2bf(float f) {
    union { float f; u32 u; } v; v.f = f;
    u32 u = v.u;
    return (ushort_t)((u + 0x7fffu + ((u >> 16) & 1u)) >> 16);   // RNE
}
__device__ inline bf16x8 load_bf8(const ushort_t* p) {
    u32x4 u = *reinterpret_cast<const u32x4*>(p);
    return __builtin_bit_cast(bf16x8, u);
}
// dual-dtype loaders for inputs (idx in elements). f32flag=1 -> array is fp32.
__device__ inline bf16x8 load8_in(const void* base, size_t idx, int f32flag) {
    if (!f32flag) return load_bf8((const ushort_t*)base + idx);
    const float* pf = (const float*)base + idx;
    f32x4 a = *reinterpret_cast<const f32x4*>(pf);
    f32x4 b = *reinterpret_cast<const f32x4*>(pf + 4);
    bf16x8 r;
#pragma unroll
    for (int j = 0; j < 4; ++j) { r[j] = (__bf16)a[j]; r[4 + j] = (__bf16)b[j]; }
    return r;
}
__device__ inline float ld_in(const void* base, size_t idx, int f32flag) {
    return f32flag ? ((const float*)base)[idx] : bf2f(((const ushort_t*)base)[idx]);
}

#define XT_STRIDE 264   // LDS tile row stride in ushorts (padded); 64*264*2 = 33.8 KB

// ---------- kernel 0: per-array dtype detector ----------
// flag = 1 iff the array is fp32. Heuristics on n u32 words:
//  - bf16 data: low-half exponent ((w>>7)&0xFF) is a plausible small-float exp -> cnt_norm ~ n
//  - fp32 random data: those bits are mid-mantissa (uniform) -> cnt_norm ~ 0.14n
//  - fp32 simple constants (1.0 etc): low16==0 and fp32 exponent plausible -> cnt_one ~ n
//  - all-zero arrays: both counters 0 -> classified bf16 (safe: zeros read correctly,
//    and the bf16 read stays within the first half of the buffer either way)
__global__ __launch_bounds__(256) void detect_kernel(const u32* __restrict__ d, int n,
                                                     int* __restrict__ flag) {
    const int t = threadIdx.x;
    int cn = 0, co = 0;
    for (int i = t; i < n; i += 256) {
        const u32 w = d[i];
        const u32 e  = (w >> 7) & 0xFF;
        const u32 fe = (w >> 23) & 0xFF;
        cn += (e >= 100 && e <= 135) ? 1 : 0;
        co += (((w & 0xFFFFu) == 0u) && fe >= 100 && fe <= 140) ? 1 : 0;
    }
    __shared__ int sn[256], so[256];
    sn[t] = cn; so[t] = co; __syncthreads();
    for (int o = 128; o; o >>= 1) {
        if (t < o) { sn[t] += sn[t + o]; so[t] += so[t + o]; }
        __syncthreads();
    }
    if (t == 0) {
        const int CN = sn[0], CO = so[0];
        const int is_f32 = (2 * CN < n) && ((2 * CO > n) || (20 * CN > n));
        *flag = is_f32 ? 1 : 0;
    }
}

// flags layout: [0]=q_emb [1]=s_emb [3]=W_lin [4]=b_lin [5]=W_out [6]=b_out [7]=ln_g [8]=ln_b
__device__ inline int f_of(const int* flags, int i) { return i < 0 ? 0 : flags[i]; }
__device__ inline int out_f32(const int* flags) {
    return flags[0] | flags[1] | flags[3] | flags[4] | flags[5] | flags[6] | flags[7] | flags[8];
}

// ---------- kernel 1: per-dilation projection ----------
// y[:, dil*128+n] = x[:, dil*128+k] @ W[dil][n][k] + b[dil][n]; W/b element offsets lw/lb.
__global__ __launch_bounds__(256) void proj_kernel(
    const void* __restrict__ X, int xi,
    const void* __restrict__ W, size_t lw,
    const void* __restrict__ Bv, size_t lb,
    ushort_t* __restrict__ Y, const int* __restrict__ flags)
{
    const int xf = f_of(flags, xi);
    const int wf = flags[3], bf = flags[4];
    const int tid  = threadIdx.x;
    const int wave = tid >> 6, lane = tid & 63;
    const int dil  = wave >> 1;
    const int n_off = (wave & 1) * 64;
    const int m0   = blockIdx.x * 64;
    const int l15  = lane & 15, quad = lane >> 4;

    f32x4 acc[4][4] = {};
    for (int kc = 0; kc < 4; ++kc) {
        bf16x8 a[4], b[4];
#pragma unroll
        for (int mt = 0; mt < 4; ++mt)
            a[mt] = load8_in(X, (size_t)(m0 + mt * 16 + l15) * 256 + dil * 128 + kc * 32 + quad * 8, xf);
#pragma unroll
        for (int nt = 0; nt < 4; ++nt)
            b[nt] = load8_in(W, lw + (size_t)dil * 16384 + (size_t)(n_off + nt * 16 + l15) * 128 + kc * 32 + quad * 8, wf);
#pragma unroll
        for (int mt = 0; mt < 4; ++mt)
#pragma unroll
            for (int nt = 0; nt < 4; ++nt)
                acc[mt][nt] = __builtin_amdgcn_mfma_f32_16x16x32_bf16(a[mt], b[nt], acc[mt][nt], 0, 0, 0);
    }
#pragma unroll
    for (int mt = 0; mt < 4; ++mt) {
#pragma unroll
        for (int nt = 0; nt < 4; ++nt) {
            const int ncol = n_off + nt * 16 + l15;
            const float bias = ld_in(Bv, lb + dil * 128 + ncol, bf);
#pragma unroll
            for (int r = 0; r < 4; ++r) {
                const int row = m0 + mt * 16 + quad * 4 + r;
                Y[(size_t)row * 256 + dil * 128 + ncol] = f2bf(acc[mt][nt][r] + bias);
            }
        }
    }
}

// ---------- kernel 1b: in-place projection (LDS-staged; X is bf16 intermediate) ----------
__global__ __launch_bounds__(256) void proj_inplace_kernel(
    ushort_t* __restrict__ X,
    const void* __restrict__ W, size_t lw,
    const void* __restrict__ Bv, size_t lb,
    const int* __restrict__ flags)
{
    __shared__ ushort_t xt[64 * XT_STRIDE];
    const int wf = flags[3], bf = flags[4];
    const int tid = threadIdx.x;
    const int m0  = blockIdx.x * 64;
#pragma unroll
    for (int i = 0; i < 8; ++i) {
        const int chunk = tid + 256 * i;
        const int row = chunk >> 5, cc = chunk & 31;
        *reinterpret_cast<u32x4*>(&xt[row * XT_STRIDE + cc * 8]) =
            *reinterpret_cast<const u32x4*>(X + (size_t)(m0 + row) * 256 + cc * 8);
    }
    __syncthreads();

    const int wave = tid >> 6, lane = tid & 63;
    const int dil  = wave >> 1;
    const int n_off = (wave & 1) * 64;
    const int l15  = lane & 15, quad = lane >> 4;

    f32x4 acc[4][4] = {};
    for (int kc = 0; kc < 4; ++kc) {
        bf16x8 a[4], b[4];
#pragma unroll
        for (int mt = 0; mt < 4; ++mt)
            a[mt] = load_bf8(&xt[(mt * 16 + l15) * XT_STRIDE + dil * 128 + kc * 32 + quad * 8]);
#pragma unroll
        for (int nt = 0; nt < 4; ++nt)
            b[nt] = load8_in(W, lw + (size_t)dil * 16384 + (size_t)(n_off + nt * 16 + l15) * 128 + kc * 32 + quad * 8, wf);
#pragma unroll
        for (int mt = 0; mt < 4; ++mt)
#pragma unroll
            for (int nt = 0; nt < 4; ++nt)
                acc[mt][nt] = __builtin_amdgcn_mfma_f32_16x16x32_bf16(a[mt], b[nt], acc[mt][nt], 0, 0, 0);
    }
#pragma unroll
    for (int mt = 0; mt < 4; ++mt) {
#pragma unroll
        for (int nt = 0; nt < 4; ++nt) {
            const int ncol = n_off + nt * 16 + l15;
            const float bias = ld_in(Bv, lb + dil * 128 + ncol, bf);
#pragma unroll
            for (int r = 0; r < 4; ++r) {
                const int row = m0 + mt * 16 + quad * 4 + r;
                X[(size_t)row * 256 + dil * 128 + ncol] = f2bf(acc[mt][nt][r] + bias);
            }
        }
    }
}

// ---------- kernel 2: fused attention + output proj + bias + residual + LN ----------
// H dtype: bf16 if h_out==0 (internal), else output dtype (bf16/fp32 by flags).
// probs_base: d_out base or nullptr; probs written at element offset 16777216 in out dtype.
// H must not alias P or V (cross-block halo reads). R may alias H (block-local rows).
__global__ __launch_bounds__(256) void fused_attn_oln_kernel(
    const ushort_t* __restrict__ P, const ushort_t* __restrict__ V,
    const void* __restrict__ R, int ri,
    const void* __restrict__ W, size_t lw,
    const void* __restrict__ Bv, size_t lb,
    const void* __restrict__ G, const void* __restrict__ Bt, size_t lg,
    void* __restrict__ H, int h_out,
    void* __restrict__ probs_base,
    const int* __restrict__ flags)
{
    __shared__ ushort_t xt[64 * XT_STRIDE];
    __shared__ float lsum[4][64], lsq[4][64];

    const int wf = flags[5], bvf = flags[6], gf = flags[7], btf = flags[8];
    const int rf = f_of(flags, ri);
    const int og = out_f32(flags);
    const int of = h_out ? og : 0;

    const int tid = threadIdx.x;
    const int m0  = blockIdx.x * 64;
    const int bb  = m0 >> 11;
    const int s0  = m0 & 2047;
    const size_t rowbase = (size_t)bb * 2048;
    const float scale = 0.17677669529663687f;   // 32^-0.5

#pragma unroll
    for (int it = 0; it < 2; ++it) {
        const int task = tid + 256 * it;
        const int r  = task & 63;
        const int dg = task >> 6;                // dil*4 + g
        const int dil = dg >> 2, g = dg & 3;
        const int dila = dil ? 1 : 3;            // DILATIONS = (3,1)
        const int s = s0 + r;
        const size_t chan0 = (size_t)dil * 128 + g * 8;

        const ushort_t* qr = P + (rowbase + s) * 256 + chan0;
        float qv[4][8];
#pragma unroll
        for (int h = 0; h < 4; ++h) {
            bf16x8 t = load_bf8(qr + h * 32);
#pragma unroll
            for (int j = 0; j < 8; ++j) qv[h][j] = (float)t[j];
        }
        float sc[5];
#pragma unroll
        for (int kk = 0; kk < 5; ++kk) {
            const int sp = s + (kk - 2) * dila;
            float a = 0.f;
            if (sp >= 0 && sp < 2048) {
                const ushort_t* kr = P + (rowbase + sp) * 256 + chan0;
#pragma unroll
                for (int h = 0; h < 4; ++h) {
                    bf16x8 t = load_bf8(kr + h * 32);
#pragma unroll
                    for (int j = 0; j < 8; ++j) a += qv[h][j] * (float)t[j];
                }
                a *= scale;
            }
            sc[kk] = a;
        }
        float mx = sc[0];
#pragma unroll
        for (int kk = 1; kk < 5; ++kk) mx = fmaxf(mx, sc[kk]);
        float p[5], sum = 0.f;
#pragma unroll
        for (int kk = 0; kk < 5; ++kk) { p[kk] = __expf(sc[kk] - mx); sum += p[kk]; }
        const float inv = 1.f / sum;
#pragma unroll
        for (int kk = 0; kk < 5; ++kk) p[kk] *= inv;

        float o[4][8] = {};
#pragma unroll
        for (int kk = 0; kk < 5; ++kk) {
            const int sp = s + (kk - 2) * dila;
            if (sp < 0 || sp >= 2048) continue;
            const ushort_t* vr = V + (rowbase + sp) * 256 + chan0;
#pragma unroll
            for (int h = 0; h < 4; ++h) {
                bf16x8 t = load_bf8(vr + h * 32);
#pragma unroll
                for (int j = 0; j < 8; ++j) o[h][j] += p[kk] * (float)t[j];
            }
        }
        // pack attn result to LDS (channel dil*128 + g*32 + d2, value o[d2&3][d2>>2])
        ushort_t* op = &xt[r * XT_STRIDE + dil * 128 + g * 32];
#pragma unroll
        for (int c = 0; c < 4; ++c) {
            u32x4 w;
#pragma unroll
            for (int t4 = 0; t4 < 4; ++t4) {
                const int d2a = c * 8 + t4 * 2, d2b = d2a + 1;
                const u32 lo = f2bf(o[d2a & 3][d2a >> 2]);
                const u32 hi = f2bf(o[d2b & 3][d2b >> 2]);
                w[t4] = lo | (hi << 16);
            }
            *reinterpret_cast<u32x4*>(op + c * 8) = w;
        }
        if (probs_base != nullptr) {
            const size_t pb = 16777216 + ((size_t)((bb * 8 + dg) * 2048 + s)) * 5;
            if (og) {
                float* pp = (float*)probs_base;
#pragma unroll
                for (int kk = 0; kk < 5; ++kk) pp[pb + kk] = p[kk];
            } else {
                ushort_t* pp = (ushort_t*)probs_base;
#pragma unroll
                for (int kk = 0; kk < 5; ++kk) pp[pb + kk] = f2bf(p[kk]);
            }
        }
    }
    __syncthreads();

    const int wave = tid >> 6, lane = tid & 63;
    const int n_off = wave * 64;
    const int l15 = lane & 15, quad = lane >> 4;

    f32x4 acc[4][4] = {};
    for (int kc = 0; kc < 8; ++kc) {
        bf16x8 a[4], b[4];
#pragma unroll
        for (int mt = 0; mt < 4; ++mt)
            a[mt] = load_bf8(&xt[(mt * 16 + l15) * XT_STRIDE + kc * 32 + quad * 8]);
#pragma unroll
        for (int nt = 0; nt < 4; ++nt)
            b[nt] = load8_in(W, lw + (size_t)(n_off + nt * 16 + l15) * 256 + kc * 32 + quad * 8, wf);
#pragma unroll
        for (int mt = 0; mt < 4; ++mt)
#pragma unroll
            for (int nt = 0; nt < 4; ++nt)
                acc[mt][nt] = __builtin_amdgcn_mfma_f32_16x16x32_bf16(a[mt], b[nt], acc[mt][nt], 0, 0, 0);
    }

    float bias[4];
#pragma unroll
    for (int nt = 0; nt < 4; ++nt) bias[nt] = ld_in(Bv, lb + n_off + nt * 16 + l15, bvf);

    float psum[4][4] = {}, psq[4][4] = {};
#pragma unroll
    for (int mt = 0; mt < 4; ++mt) {
#pragma unroll
        for (int rr = 0; rr < 4; ++rr) {
            const size_t rrow = (size_t)(m0 + mt * 16 + quad * 4 + rr) * 256 + l15;
#pragma unroll
            for (int nt = 0; nt < 4; ++nt) {
                float v = acc[mt][nt][rr] + bias[nt] + ld_in(R, rrow + n_off + nt * 16, rf);
                acc[mt][nt][rr] = v;
                psum[mt][rr] += v;
                psq[mt][rr]  += v * v;
            }
        }
    }
#pragma unroll
    for (int off = 1; off <= 8; off <<= 1) {
#pragma unroll
        for (int mt = 0; mt < 4; ++mt)
#pragma unroll
            for (int rr = 0; rr < 4; ++rr) {
                psum[mt][rr] += __shfl_xor(psum[mt][rr], off);
                psq[mt][rr]  += __shfl_xor(psq[mt][rr],  off);
            }
    }
    if (l15 == 0) {
#pragma unroll
        for (int mt = 0; mt < 4; ++mt)
#pragma unroll
            for (int rr = 0; rr < 4; ++rr) {
                const int row = mt * 16 + quad * 4 + rr;
                lsum[wave][row] = psum[mt][rr];
                lsq[wave][row]  = psq[mt][rr];
            }
    }
    __syncthreads();

    float gl[4], bl[4];
#pragma unroll
    for (int nt = 0; nt < 4; ++nt) {
        gl[nt] = ld_in(G,  lg + n_off + nt * 16 + l15, gf);
        bl[nt] = ld_in(Bt, lg + n_off + nt * 16 + l15, btf);
    }
#pragma unroll
    for (int mt = 0; mt < 4; ++mt) {
#pragma unroll
        for (int rr = 0; rr < 4; ++rr) {
            const int row = mt * 16 + quad * 4 + rr;
            const float sm = lsum[0][row] + lsum[1][row] + lsum[2][row] + lsum[3][row];
            const float q2 = lsq[0][row]  + lsq[1][row]  + lsq[2][row]  + lsq[3][row];
            const float mu  = sm * (1.f / 256.f);
            const float var = q2 * (1.f / 256.f) - mu * mu;
            const float rs  = rsqrtf(var + 1e-5f);
            const size_t hrow = (size_t)(m0 + row) * 256 + l15;
#pragma unroll
            for (int nt = 0; nt < 4; ++nt) {
                const float hv = (acc[mt][nt][rr] - mu) * rs * gl[nt] + bl[nt];
                if (of) ((float*)H)[hrow + n_off + nt * 16] = hv;
                else    ((ushort_t*)H)[hrow + n_off + nt * 16] = f2bf(hv);
            }
        }
    }
}

// ---------- launch ----------
extern "C" void kernel_launch(void* const* d_in, const int* in_sizes, int n_in,
                              void* d_out, int out_size, void* d_ws, size_t ws_size,
                              hipStream_t stream) {
    const void* q_emb = d_in[0];
    const void* s_emb = d_in[1];
    const void* W_lin = d_in[3];   // (3,2,128,128) layer stride 32768 elems
    const void* b_lin = d_in[4];   // (3,2,128)     layer stride 256
    const void* W_out = d_in[5];   // (3,256,256)   layer stride 65536
    const void* b_out = d_in[6];   // (3,256)       layer stride 256
    const void* ln_g  = d_in[7];
    const void* ln_b  = d_in[8];

    const size_t SLOT = 16777216;
    int*      flags = (int*)d_ws;                      // 16 ints
    ushort_t* SA = (ushort_t*)((char*)d_ws + 256);     // hq
    ushort_t* SB = SA + SLOT;                          // hs
    ushort_t* SC = SA + 2 * SLOT;                      // proj scratch
    // d_ws footprint: 256 B + 3 x 33.55 MB = 100.7 MB (round-2 proved resident)

    const dim3 blk(256);
    detect_kernel<<<1, blk, 0, stream>>>((const u32*)q_emb, 16384, flags + 0);
    detect_kernel<<<1, blk, 0, stream>>>((const u32*)s_emb, 16384, flags + 1);
    detect_kernel<<<1, blk, 0, stream>>>((const u32*)W_lin, 16384, flags + 3);
    detect_kernel<<<1, blk, 0, stream>>>((const u32*)b_lin,   384, flags + 4);
    detect_kernel<<<1, blk, 0, stream>>>((const u32*)W_out, 16384, flags + 5);
    detect_kernel<<<1, blk, 0, stream>>>((const u32*)b_out,   384, flags + 6);
    detect_kernel<<<1, blk, 0, stream>>>((const u32*)ln_g,    384, flags + 7);
    detect_kernel<<<1, blk, 0, stream>>>((const u32*)ln_b,    384, flags + 8);

    // ---- stage A: hq = LN(q_emb + mha(q_emb)) -> SA (bf16)
    proj_kernel<<<1024, blk, 0, stream>>>(q_emb, 0, W_lin, 0, b_lin, 0, SC, flags);
    fused_attn_oln_kernel<<<1024, blk, 0, stream>>>(SC, SC, q_emb, 0,
        W_out, 0, b_out, 0, ln_g, ln_b, 0, SA, 0, nullptr, flags);
    // ---- stage B: hs = LN(s_emb + mha(s_emb)) -> SB (bf16), probs -> d_out[16777216..]
    proj_kernel<<<1024, blk, 0, stream>>>(s_emb, 1, W_lin, 32768, b_lin, 256, SC, flags);
    fused_attn_oln_kernel<<<1024, blk, 0, stream>>>(SC, SC, s_emb, 1,
        W_out, 65536, b_out, 256, ln_g, ln_b, 256, SB, 0, d_out, flags);
    // ---- stage C: z = LN(hq + mha(q=k=hq, v=hs)) -> d_out (out dtype)
    proj_kernel<<<1024, blk, 0, stream>>>(SA, -1, W_lin, 65536, b_lin, 512, SC, flags);   // QK proj
    proj_inplace_kernel<<<1024, blk, 0, stream>>>(SB, W_lin, 65536, b_lin, 512, flags);   // V proj in-place
    fused_attn_oln_kernel<<<1024, blk, 0, stream>>>(SC, SB, SA, -1,
        W_out, 131072, b_out, 512, ln_g, ln_b, 512, d_out, 1, nullptr, flags);
}